// Round 1
// baseline (419.961 us; speedup 1.0000x reference)
//
#include <hip/hip_runtime.h>
#include <math.h>

#define NT 512
#define BR 16
#define NROWS 32768

typedef __attribute__((ext_vector_type(8))) short bf16x8;
typedef __attribute__((ext_vector_type(4))) float f32x4;
typedef __attribute__((ext_vector_type(2))) unsigned int u32x2;

struct GridConsts { float T[20][4]; float F[20][4]; };

__device__ __forceinline__ unsigned pk2(float a, float b){
  unsigned ua = __float_as_uint(a); ua += 0x7FFFu + ((ua>>16)&1u);
  unsigned ub = __float_as_uint(b); ub += 0x7FFFu + ((ub>>16)&1u);
  return (ua>>16) | (ub & 0xFFFF0000u);
}
__device__ __forceinline__ unsigned short bf1(float a){
  unsigned ua = __float_as_uint(a); ua += 0x7FFFu + ((ua>>16)&1u);
  return (unsigned short)(ua>>16);
}
__device__ __forceinline__ float silu_f(float x){
  return __fdividef(x, 1.0f + __expf(-x));
}

#define MFMA(a,b,c) __builtin_amdgcn_mfma_f32_16x16x32_bf16((a),(b),(c),0,0,0)

__global__ void prep_weights(const float* __restrict__ Ws, const float* __restrict__ Wv,
                             const float* __restrict__ W2, const float* __restrict__ Wos,
                             const float* __restrict__ Wov, unsigned short* __restrict__ o){
  int i = blockIdx.x*512 + threadIdx.x;
  if (i >= 327680) return;
  float val;
  if (i < 65536)       val = Ws[i];
  else if (i < 98304)  val = Wv[i-65536];
  else if (i < 229376) val = W2[i-98304];
  else if (i < 294912) val = Wos[i-229376];
  else                 val = Wov[i-294912];
  o[i] = bf1(val);
}

// sep_act on one wave's accumulators; writes bf16 emb tile to LDS (swizzled).
// acc[m][ht2] holds D[col=r=l16][row = 32w+16*ht2+4*lq+j], j=0..3.
__device__ __forceinline__ void sep_store(const GridConsts& gc, const f32x4 (&acc)[4][2],
                                          char* smem, int w, int l16, int lq){
#pragma unroll
  for (int ht2=0; ht2<2; ++ht2){
    float y[4][4];
#pragma unroll
    for (int j=0;j<4;++j){
      float x0=acc[0][ht2][j], x1=acc[1][ht2][j], x2=acc[2][ht2][j], x3=acc[3][ht2][j];
      y[0][j] = silu_f(x0);                    // scalar (l=0) branch
      float a1=0.f, a2=0.f, a3=0.f;
      for (int p=0;p<20;++p){                  // S2 grid: project, silu, project back
        float xg = gc.T[p][0]*x0;
        xg = fmaf(gc.T[p][1], x1, xg);
        xg = fmaf(gc.T[p][2], x2, xg);
        xg = fmaf(gc.T[p][3], x3, xg);
        float g = silu_f(xg);
        a1 = fmaf(gc.F[p][1], g, a1);
        a2 = fmaf(gc.F[p][2], g, a2);
        a3 = fmaf(gc.F[p][3], g, a3);
      }
      y[1][j]=a1; y[2][j]=a2; y[3][j]=a3;
    }
    int h0 = 32*w + 16*ht2 + 4*lq;
#pragma unroll
    for (int m=0;m<4;++m){
      u32x2 p; p.x = pk2(y[m][0], y[m][1]); p.y = pk2(y[m][2], y[m][3]);
      int off = (l16*2048 + m*512 + h0*2) ^ ((l16&7)<<4);
      *(u32x2*)(smem + off) = p;
    }
  }
}

__global__ void __launch_bounds__(NT) nt_fused(
    const float* __restrict__ s, const float* __restrict__ v,
    const unsigned short* __restrict__ wbf,
    const float* __restrict__ bs, const float* __restrict__ b2,
    const float* __restrict__ bos,
    const float* __restrict__ gamma_s, const float* __restrict__ beta_s,
    const float* __restrict__ gamma_v,
    float* __restrict__ out, GridConsts gc)
{
  __shared__ __align__(128) char smem[32768];
  const int tid = threadIdx.x;
  const int w = tid >> 6;
  const int lane = tid & 63;
  const int l16 = lane & 15, lq = lane >> 4;
  const int row0 = blockIdx.x * BR;

  // ---- stage s tile -> bf16 LDS [16][256] (swizzled), base 0 ----
#pragma unroll
  for (int it=0; it<2; ++it){
    int i = tid + it*512;               // 0..1023  (16 rows x 64 float4)
    int r = i >> 6, c = (i & 63) * 4;
    f32x4 fv = *(const f32x4*)(s + (size_t)(row0+r)*256 + c);
    u32x2 p; p.x = pk2(fv[0], fv[1]); p.y = pk2(fv[2], fv[3]);
    int off = (r*512 + c*2) ^ ((r&7)<<4);
    *(u32x2*)(smem + off) = p;
  }
  // ---- stage v tile -> bf16 LDS [16][3][128] (transposed, swizzled), base 8192 ----
#pragma unroll
  for (int it=0; it<3; ++it){
    int i = tid + it*512;               // 0..1535  (16 rows x 96 float4)
    int r = i / 96, fb = (i % 96) * 4;
    f32x4 fv = *(const f32x4*)(v + (size_t)(row0+r)*384 + fb);
#pragma unroll
    for (int k2=0;k2<4;++k2){
      int flat = fb + k2;
      int c = flat/3, m3 = flat%3;      // v[r][c][m] -> vT[r][m][c]
      int off = 8192 + ((r*768 + m3*256 + c*2) ^ ((r&7)<<4));
      *(unsigned short*)(smem + off) = bf1(fv[k2]);
    }
  }
  __syncthreads();

  const unsigned short* Ws  = wbf;
  const unsigned short* Wv  = wbf + 65536;
  const unsigned short* W20 = wbf + 98304;
  const unsigned short* W21 = wbf + 163840;
  const unsigned short* Wos = wbf + 229376;
  const unsigned short* Wov = wbf + 294912;

  const f32x4 zero = {0.f,0.f,0.f,0.f};
  f32x4 acc[4][2];
#pragma unroll
  for (int m=0;m<4;++m){ acc[m][0]=zero; acc[m][1]=zero; }

  // ---- GEMM1: emb = [s@Ws^T ; vT@Wv^T]  (A=weights, B=activation rows) ----
  {
    const int h0 = 32*w + l16, h1 = h0 + 16;
#pragma unroll
    for (int ks=0;ks<8;++ks){
      int k = ks*32 + lq*8;
      bf16x8 a0 = *(const bf16x8*)(Ws + h0*256 + k);
      bf16x8 a1 = *(const bf16x8*)(Ws + h1*256 + k);
      bf16x8 b  = *(const bf16x8*)(smem + ((l16*512 + k*2) ^ ((l16&7)<<4)));
      acc[0][0] = MFMA(a0,b,acc[0][0]);
      acc[0][1] = MFMA(a1,b,acc[0][1]);
    }
#pragma unroll
    for (int ks=0;ks<4;++ks){
      int k = ks*32 + lq*8;
      bf16x8 a0 = *(const bf16x8*)(Wv + (32*w + l16)*128 + k);
      bf16x8 a1 = *(const bf16x8*)(Wv + (32*w + 16 + l16)*128 + k);
#pragma unroll
      for (int m3=0;m3<3;++m3){
        bf16x8 b = *(const bf16x8*)(smem + (8192 + ((l16*768 + m3*256 + k*2) ^ ((l16&7)<<4))));
        acc[1+m3][0] = MFMA(a0,b,acc[1+m3][0]);
        acc[1+m3][1] = MFMA(a1,b,acc[1+m3][1]);
      }
    }
  }
  acc[0][0] += *(const f32x4*)(bs + 32*w + 4*lq);
  acc[0][1] += *(const f32x4*)(bs + 32*w + 16 + 4*lq);

  __syncthreads();                       // all waves done reading s/v tiles
  sep_store(gc, acc, smem, w, l16, lq);  // emb -> LDS [16][4][256]
  __syncthreads();

  // ---- GEMM2: per-m weights W2[0]/W2[1], K=256 ----
  f32x4 acc2[4][2];
#pragma unroll
  for (int m=0;m<4;++m){ acc2[m][0]=zero; acc2[m][1]=zero; }
  {
    const int h0 = 32*w + l16, h1 = h0 + 16;
#pragma unroll
    for (int ks=0;ks<8;++ks){
      int k = ks*32 + lq*8;
      bf16x8 a00 = *(const bf16x8*)(W20 + h0*256 + k);
      bf16x8 a01 = *(const bf16x8*)(W20 + h1*256 + k);
      bf16x8 a10 = *(const bf16x8*)(W21 + h0*256 + k);
      bf16x8 a11 = *(const bf16x8*)(W21 + h1*256 + k);
#pragma unroll
      for (int m=0;m<4;++m){
        bf16x8 b = *(const bf16x8*)(smem + ((l16*2048 + m*512 + k*2) ^ ((l16&7)<<4)));
        acc2[m][0] = MFMA((m==0)?a00:a10, b, acc2[m][0]);
        acc2[m][1] = MFMA((m==0)?a01:a11, b, acc2[m][1]);
      }
    }
  }
  acc2[0][0] += *(const f32x4*)(b2 + 32*w + 4*lq);
  acc2[0][1] += *(const f32x4*)(b2 + 32*w + 16 + 4*lq);

  __syncthreads();
  sep_store(gc, acc2, smem, w, l16, lq); // emb2 -> LDS (in place)
  __syncthreads();

  // ---- GEMM3: out_s (Wos, 256 out) + out_v (Wov, 128 out x 3m) ----
  f32x4 accS[2]; accS[0]=zero; accS[1]=zero;
  f32x4 accV[3]; accV[0]=zero; accV[1]=zero; accV[2]=zero;
  {
    const int hs0 = 32*w + l16, hs1 = hs0 + 16;
    const int hv  = 16*w + l16;
#pragma unroll
    for (int ks=0;ks<8;++ks){
      int k = ks*32 + lq*8;
      bf16x8 as0 = *(const bf16x8*)(Wos + hs0*256 + k);
      bf16x8 as1 = *(const bf16x8*)(Wos + hs1*256 + k);
      bf16x8 av  = *(const bf16x8*)(Wov + hv*256 + k);
      bf16x8 b0  = *(const bf16x8*)(smem + ((l16*2048 + 0*512 + k*2) ^ ((l16&7)<<4)));
      accS[0] = MFMA(as0,b0,accS[0]);
      accS[1] = MFMA(as1,b0,accS[1]);
#pragma unroll
      for (int m3=0;m3<3;++m3){
        bf16x8 bm = *(const bf16x8*)(smem + ((l16*2048 + (1+m3)*512 + k*2) ^ ((l16&7)<<4)));
        accV[m3] = MFMA(av, bm, accV[m3]);
      }
    }
  }
  accS[0] += *(const f32x4*)(bos + 32*w + 4*lq);
  accS[1] += *(const f32x4*)(bos + 32*w + 16 + 4*lq);

  // ---- epilogue A: out_s = LN(s + out_s) ----
  __syncthreads();                       // done reading emb2
  {
    float* scr = (float*)smem;           // [16][260] f32 (padded)
    *(f32x4*)(scr + l16*260 + 32*w + 4*lq)      = accS[0];
    *(f32x4*)(scr + l16*260 + 32*w + 16 + 4*lq) = accS[1];
  }
  __syncthreads();
  {
    int rr = tid >> 5, g = tid & 31, c0 = g*8;
    const float* srow = s + (size_t)(row0+rr)*256 + c0;
    f32x4 s0 = *(const f32x4*)srow, s1 = *(const f32x4*)(srow+4);
    const float* scr = (const float*)smem + rr*260 + c0;
    f32x4 o0 = *(const f32x4*)scr, o1 = *(const f32x4*)(scr+4);
    float xv[8]; float sum=0.f, sq=0.f;
#pragma unroll
    for (int k2=0;k2<4;++k2){ xv[k2]=s0[k2]+o0[k2]; xv[4+k2]=s1[k2]+o1[k2]; }
#pragma unroll
    for (int k2=0;k2<8;++k2){ sum += xv[k2]; sq += xv[k2]*xv[k2]; }
#pragma unroll
    for (int mk=1; mk<32; mk<<=1){ sum += __shfl_xor(sum, mk, 64); sq += __shfl_xor(sq, mk, 64); }
    float mu = sum*(1.0f/256.0f);
    float var = sq*(1.0f/256.0f) - mu*mu;
    float rs = rsqrtf(var + 1e-5f);
    f32x4 ga = *(const f32x4*)(gamma_s+c0), gb = *(const f32x4*)(gamma_s+c0+4);
    f32x4 ba = *(const f32x4*)(beta_s+c0),  bb = *(const f32x4*)(beta_s+c0+4);
    f32x4 r0, r1;
#pragma unroll
    for (int k2=0;k2<4;++k2){
      r0[k2] = (xv[k2]  -mu)*rs*ga[k2] + ba[k2];
      r1[k2] = (xv[4+k2]-mu)*rs*gb[k2] + bb[k2];
    }
    float* orow = out + (size_t)(row0+rr)*256 + c0;
    *(f32x4*)orow = r0; *(f32x4*)(orow+4) = r1;
  }
  // ---- epilogue B: equivariant vector norm ----
  __syncthreads();
  {
    float* scr = (float*)smem;           // [16][388] f32 (padded), [r][m*128+c]
#pragma unroll
    for (int m3=0;m3<3;++m3)
      *(f32x4*)(scr + l16*388 + m3*128 + 16*w + 4*lq) = accV[m3];
  }
  __syncthreads();
  {
    int rr = tid >> 5, g = tid & 31, c0 = g*4;
    const float* vrow = v + (size_t)(row0+rr)*384 + c0*3;
    f32x4 vv0 = *(const f32x4*)(vrow);
    f32x4 vv1 = *(const f32x4*)(vrow+4);
    f32x4 vv2 = *(const f32x4*)(vrow+8);
    const float* scr = (const float*)smem + rr*388;
    float vr[12]; float ss = 0.f;
#pragma unroll
    for (int f=0; f<12; ++f){
      int k = f/3, m3 = f%3;
      float base = (f<4) ? vv0[f] : ((f<8) ? vv1[f-4] : vv2[f-8]);
      float val = base + scr[m3*128 + c0 + k];
      vr[f] = val; ss += val*val;
    }
#pragma unroll
    for (int mk=1; mk<32; mk<<=1) ss += __shfl_xor(ss, mk, 64);
    float inv = rsqrtf(ss*(1.0f/128.0f) + 1e-5f);
    f32x4 gvv = *(const f32x4*)(gamma_v + c0);
    f32x4 o0, o1, o2;
#pragma unroll
    for (int f=0; f<12; ++f){
      float val = vr[f]*inv*gvv[f/3];
      if (f<4) o0[f]=val; else if (f<8) o1[f-4]=val; else o2[f-8]=val;
    }
    float* orow = out + (size_t)NROWS*256 + (size_t)(row0+rr)*384 + c0*3;
    *(f32x4*)(orow) = o0; *(f32x4*)(orow+4) = o1; *(f32x4*)(orow+8) = o2;
  }
}

extern "C" void kernel_launch(void* const* d_in, const int* in_sizes, int n_in,
                              void* d_out, int out_size, void* d_ws, size_t ws_size,
                              hipStream_t stream)
{
  const float* s   = (const float*)d_in[0];
  const float* v   = (const float*)d_in[1];
  const float* Ws  = (const float*)d_in[2];
  const float* bs  = (const float*)d_in[3];
  const float* Wv  = (const float*)d_in[4];
  const float* W2  = (const float*)d_in[5];
  const float* b2  = (const float*)d_in[6];
  const float* Wos = (const float*)d_in[7];
  const float* bos = (const float*)d_in[8];
  const float* Wov = (const float*)d_in[9];
  const float* gs  = (const float*)d_in[10];
  const float* bts = (const float*)d_in[11];
  const float* gv  = (const float*)d_in[12];
  float* out = (float*)d_out;
  unsigned short* wbf = (unsigned short*)d_ws;   // 655,360 B of bf16 weights

  prep_weights<<<640, 512, 0, stream>>>(Ws, Wv, W2, Wos, Wov, wbf);

  GridConsts gc;
  {
    const double xb[4] = {-0.8611363115940526, -0.33998104358485626,
                           0.33998104358485626, 0.8611363115940526};
    const double wb[4] = { 0.34785484513745385, 0.6521451548625462,
                           0.6521451548625462,  0.34785484513745385};
    const double PI = 3.14159265358979323846;
    const double wa = 2.0*PI/5.0;
    const double k0 = 0.5/sqrt(PI), k1 = sqrt(3.0/(4.0*PI));
    for (int b=0;b<4;++b){
      double sb = sqrt(1.0 - xb[b]*xb[b]);
      for (int a=0;a<5;++a){
        double al = 2.0*PI*(double)a/5.0;
        double X = sb*cos(al), Y = sb*sin(al), Z = xb[b];
        int p = b*5+a;
        double t0=k0, t1=k1*Y, t2=k1*Z, t3=k1*X;
        gc.T[p][0]=(float)t0; gc.T[p][1]=(float)t1; gc.T[p][2]=(float)t2; gc.T[p][3]=(float)t3;
        double ww = wb[b]*wa;
        gc.F[p][0]=(float)(t0*ww); gc.F[p][1]=(float)(t1*ww);
        gc.F[p][2]=(float)(t2*ww); gc.F[p][3]=(float)(t3*ww);
      }
    }
  }

  nt_fused<<<NROWS/BR, NT, 0, stream>>>(s, v, wbf, bs, b2, bos, gs, bts, gv, out, gc);
}

// Round 2
// 301.992 us; speedup vs baseline: 1.3906x; 1.3906x over previous
//
#include <hip/hip_runtime.h>
#include <math.h>

#define NT 512
#define BR 16
#define NROWS 32768

typedef __attribute__((ext_vector_type(8))) short bf16x8;
typedef __attribute__((ext_vector_type(4))) float f32x4;
typedef __attribute__((ext_vector_type(2))) unsigned int u32x2;

__device__ __forceinline__ unsigned pk2(float a, float b){
  unsigned ua = __float_as_uint(a); ua += 0x7FFFu + ((ua>>16)&1u);
  unsigned ub = __float_as_uint(b); ub += 0x7FFFu + ((ub>>16)&1u);
  return (ua>>16) | (ub & 0xFFFF0000u);
}
__device__ __forceinline__ unsigned short bf1(float a){
  unsigned ua = __float_as_uint(a); ua += 0x7FFFu + ((ua>>16)&1u);
  return (unsigned short)(ua>>16);
}
__device__ __forceinline__ float silu_f(float x){
  return __fdividef(x, 1.0f + __expf(-x));
}

#define MFMA(a,b,c) __builtin_amdgcn_mfma_f32_16x16x32_bf16((a),(b),(c),0,0,0)

__global__ void prep_weights(const float* __restrict__ Ws, const float* __restrict__ Wv,
                             const float* __restrict__ W2, const float* __restrict__ Wos,
                             const float* __restrict__ Wov, unsigned short* __restrict__ o){
  int i = blockIdx.x*512 + threadIdx.x;
  if (i >= 327680) return;
  float val;
  if (i < 65536)       val = Ws[i];
  else if (i < 98304)  val = Wv[i-65536];
  else if (i < 229376) val = W2[i-98304];
  else if (i < 294912) val = Wos[i-229376];
  else                 val = Wov[i-294912];
  o[i] = bf1(val);
}

// ---- SeparableS2Activation for lmax=1 on the 4x5 grid, fully unrolled with
// literal constants (ring-factored).  Constants:
//   k0=0.28209479, k1*xb(outer)=0.42075337, k1*xb(inner)=0.16611559
//   k1*sb(outer)=0.24839288, k1*sb(inner)=0.45949758
//   WZ = w*k1*xb: outer 0.18392278, inner 0.13613335
//   WA = w*k1*sb: outer 0.10857931, inner 0.37656275
//   C1 = WA*sin(a), C3 = WA*cos(a) for a = 72,144 deg.
__device__ __forceinline__ void s2act(float x0, float x1, float x2, float x3,
                                      float yy[4]){
  yy[0] = silu_f(x0);
  const float t   = 0.28209479f * x0;
  const float cb0 = __builtin_fmaf(-0.42075337f, x2, t);
  const float cb1 = __builtin_fmaf(-0.16611559f, x2, t);
  const float cb2 = __builtin_fmaf( 0.16611559f, x2, t);
  const float cb3 = __builtin_fmaf( 0.42075337f, x2, t);
  const float d1o = 0.24839288f * x1, d3o = 0.24839288f * x3;
  const float d1i = 0.45949758f * x1, d3i = 0.45949758f * x3;
  float a1 = 0.f, a2 = 0.f, a3 = 0.f;
#define SILU_G(xg, g) { float _e = __expf(-(xg)); (g) = __fdividef((xg), 1.0f + _e); }
#define RING(cb, d1v, d3v, WZ, WA, C11, C12, C31, C32) { \
    float g, xg; \
    xg = (cb) + (d3v); SILU_G(xg,g); \
    a2 = __builtin_fmaf((WZ), g, a2); a3 = __builtin_fmaf((WA), g, a3); \
    xg = __builtin_fmaf(0.30901699f,(d3v), __builtin_fmaf(0.95105652f,(d1v),(cb))); SILU_G(xg,g); \
    a1 = __builtin_fmaf((C11),g,a1); a2 = __builtin_fmaf((WZ),g,a2); a3 = __builtin_fmaf((C31),g,a3); \
    xg = __builtin_fmaf(-0.80901699f,(d3v), __builtin_fmaf(0.58778525f,(d1v),(cb))); SILU_G(xg,g); \
    a1 = __builtin_fmaf((C12),g,a1); a2 = __builtin_fmaf((WZ),g,a2); a3 = __builtin_fmaf(-(C32),g,a3); \
    xg = __builtin_fmaf(-0.80901699f,(d3v), __builtin_fmaf(-0.58778525f,(d1v),(cb))); SILU_G(xg,g); \
    a1 = __builtin_fmaf(-(C12),g,a1); a2 = __builtin_fmaf((WZ),g,a2); a3 = __builtin_fmaf(-(C32),g,a3); \
    xg = __builtin_fmaf(0.30901699f,(d3v), __builtin_fmaf(-0.95105652f,(d1v),(cb))); SILU_G(xg,g); \
    a1 = __builtin_fmaf(-(C11),g,a1); a2 = __builtin_fmaf((WZ),g,a2); a3 = __builtin_fmaf((C31),g,a3); \
  }
  RING(cb0, d1o, d3o, -0.18392278f, 0.10857931f, 0.10326505f, 0.06382132f, 0.03355286f, 0.08784251f)
  RING(cb1, d1i, d3i, -0.13613335f, 0.37656275f, 0.35813245f, 0.22133803f, 0.11636429f, 0.30464566f)
  RING(cb2, d1i, d3i,  0.13613335f, 0.37656275f, 0.35813245f, 0.22133803f, 0.11636429f, 0.30464566f)
  RING(cb3, d1o, d3o,  0.18392278f, 0.10857931f, 0.10326505f, 0.06382132f, 0.03355286f, 0.08784251f)
#undef RING
#undef SILU_G
  yy[1] = a1; yy[2] = a2; yy[3] = a3;
}

// sep_act on one wave's accumulators; writes bf16 emb tile to LDS (swizzled).
// acc[m][ht2] holds D[col=r=l16][row = 32w+16*ht2+4*lq+j], j=0..3.
__device__ __forceinline__ void sep_store(const f32x4 (&acc)[4][2],
                                          char* smem, int w, int l16, int lq){
#pragma unroll
  for (int ht2=0; ht2<2; ++ht2){
    float y[4][4];
#pragma unroll
    for (int j=0;j<4;++j){
      float yy[4];
      s2act(acc[0][ht2][j], acc[1][ht2][j], acc[2][ht2][j], acc[3][ht2][j], yy);
#pragma unroll
      for (int m=0;m<4;++m) y[m][j] = yy[m];
    }
    int h0 = 32*w + 16*ht2 + 4*lq;
#pragma unroll
    for (int m=0;m<4;++m){
      u32x2 p; p.x = pk2(y[m][0], y[m][1]); p.y = pk2(y[m][2], y[m][3]);
      int off = (l16*2048 + m*512 + h0*2) ^ ((l16&7)<<4);
      *(u32x2*)(smem + off) = p;
    }
  }
}

__global__ void __launch_bounds__(NT, 4) nt_fused(
    const float* __restrict__ s, const float* __restrict__ v,
    const unsigned short* __restrict__ wbf,
    const float* __restrict__ bs, const float* __restrict__ b2,
    const float* __restrict__ bos,
    const float* __restrict__ gamma_s, const float* __restrict__ beta_s,
    const float* __restrict__ gamma_v,
    float* __restrict__ out)
{
  __shared__ __align__(128) char smem[32768];
  const int tid = threadIdx.x;
  const int w = tid >> 6;
  const int lane = tid & 63;
  const int l16 = lane & 15, lq = lane >> 4;
  const int row0 = blockIdx.x * BR;

  // ---- stage s tile -> bf16 LDS [16][256] (swizzled), base 0 ----
#pragma unroll
  for (int it=0; it<2; ++it){
    int i = tid + it*512;               // 0..1023  (16 rows x 64 float4)
    int r = i >> 6, c = (i & 63) * 4;
    f32x4 fv = *(const f32x4*)(s + (size_t)(row0+r)*256 + c);
    u32x2 p; p.x = pk2(fv[0], fv[1]); p.y = pk2(fv[2], fv[3]);
    int off = (r*512 + c*2) ^ ((r&7)<<4);
    *(u32x2*)(smem + off) = p;
  }
  // ---- stage v tile -> bf16 LDS [16][3][128] (transposed, swizzled), base 8192 ----
#pragma unroll
  for (int it=0; it<3; ++it){
    int i = tid + it*512;               // 0..1535  (16 rows x 96 float4)
    int r = i / 96, fb = (i % 96) * 4;
    f32x4 fv = *(const f32x4*)(v + (size_t)(row0+r)*384 + fb);
#pragma unroll
    for (int k2=0;k2<4;++k2){
      int flat = fb + k2;
      int c = flat/3, m3 = flat%3;      // v[r][c][m] -> vT[r][m][c]
      int off = 8192 + ((r*768 + m3*256 + c*2) ^ ((r&7)<<4));
      *(unsigned short*)(smem + off) = bf1(fv[k2]);
    }
  }
  __syncthreads();

  const unsigned short* Ws  = wbf;
  const unsigned short* Wv  = wbf + 65536;
  const unsigned short* W20 = wbf + 98304;
  const unsigned short* W21 = wbf + 163840;
  const unsigned short* Wos = wbf + 229376;
  const unsigned short* Wov = wbf + 294912;

  const f32x4 zero = {0.f,0.f,0.f,0.f};
  f32x4 acc[4][2];
#pragma unroll
  for (int m=0;m<4;++m){ acc[m][0]=zero; acc[m][1]=zero; }

  // ---- GEMM1: emb = [s@Ws^T ; vT@Wv^T]  (A=weights, B=activation rows) ----
  {
    const int h0 = 32*w + l16, h1 = h0 + 16;
#pragma unroll
    for (int ks=0;ks<8;++ks){
      int k = ks*32 + lq*8;
      bf16x8 a0 = *(const bf16x8*)(Ws + h0*256 + k);
      bf16x8 a1 = *(const bf16x8*)(Ws + h1*256 + k);
      bf16x8 b  = *(const bf16x8*)(smem + ((l16*512 + k*2) ^ ((l16&7)<<4)));
      acc[0][0] = MFMA(a0,b,acc[0][0]);
      acc[0][1] = MFMA(a1,b,acc[0][1]);
    }
#pragma unroll
    for (int ks=0;ks<4;++ks){
      int k = ks*32 + lq*8;
      bf16x8 a0 = *(const bf16x8*)(Wv + (32*w + l16)*128 + k);
      bf16x8 a1 = *(const bf16x8*)(Wv + (32*w + 16 + l16)*128 + k);
#pragma unroll
      for (int m3=0;m3<3;++m3){
        bf16x8 b = *(const bf16x8*)(smem + (8192 + ((l16*768 + m3*256 + k*2) ^ ((l16&7)<<4))));
        acc[1+m3][0] = MFMA(a0,b,acc[1+m3][0]);
        acc[1+m3][1] = MFMA(a1,b,acc[1+m3][1]);
      }
    }
  }
  acc[0][0] += *(const f32x4*)(bs + 32*w + 4*lq);
  acc[0][1] += *(const f32x4*)(bs + 32*w + 16 + 4*lq);

  __syncthreads();                       // all waves done reading s/v tiles
  sep_store(acc, smem, w, l16, lq);      // emb -> LDS [16][4][256]
  __syncthreads();

  // ---- GEMM2: per-m weights W2[0]/W2[1], K=256 ----
  f32x4 acc2[4][2];
#pragma unroll
  for (int m=0;m<4;++m){ acc2[m][0]=zero; acc2[m][1]=zero; }
  {
    const int h0 = 32*w + l16, h1 = h0 + 16;
#pragma unroll
    for (int ks=0;ks<8;++ks){
      int k = ks*32 + lq*8;
      bf16x8 a00 = *(const bf16x8*)(W20 + h0*256 + k);
      bf16x8 a01 = *(const bf16x8*)(W20 + h1*256 + k);
      bf16x8 a10 = *(const bf16x8*)(W21 + h0*256 + k);
      bf16x8 a11 = *(const bf16x8*)(W21 + h1*256 + k);
#pragma unroll
      for (int m=0;m<4;++m){
        bf16x8 b = *(const bf16x8*)(smem + ((l16*2048 + m*512 + k*2) ^ ((l16&7)<<4)));
        acc2[m][0] = MFMA((m==0)?a00:a10, b, acc2[m][0]);
        acc2[m][1] = MFMA((m==0)?a01:a11, b, acc2[m][1]);
      }
    }
  }
  acc2[0][0] += *(const f32x4*)(b2 + 32*w + 4*lq);
  acc2[0][1] += *(const f32x4*)(b2 + 32*w + 16 + 4*lq);

  __syncthreads();
  sep_store(acc2, smem, w, l16, lq);     // emb2 -> LDS (in place)
  __syncthreads();

  // ---- GEMM3: out_s (Wos, 256 out) + out_v (Wov, 128 out x 3m) ----
  f32x4 accS[2]; accS[0]=zero; accS[1]=zero;
  f32x4 accV[3]; accV[0]=zero; accV[1]=zero; accV[2]=zero;
  {
    const int hs0 = 32*w + l16, hs1 = hs0 + 16;
    const int hv  = 16*w + l16;
#pragma unroll
    for (int ks=0;ks<8;++ks){
      int k = ks*32 + lq*8;
      bf16x8 as0 = *(const bf16x8*)(Wos + hs0*256 + k);
      bf16x8 as1 = *(const bf16x8*)(Wos + hs1*256 + k);
      bf16x8 av  = *(const bf16x8*)(Wov + hv*256 + k);
      bf16x8 b0  = *(const bf16x8*)(smem + ((l16*2048 + 0*512 + k*2) ^ ((l16&7)<<4)));
      accS[0] = MFMA(as0,b0,accS[0]);
      accS[1] = MFMA(as1,b0,accS[1]);
#pragma unroll
      for (int m3=0;m3<3;++m3){
        bf16x8 bm = *(const bf16x8*)(smem + ((l16*2048 + (1+m3)*512 + k*2) ^ ((l16&7)<<4)));
        accV[m3] = MFMA(av, bm, accV[m3]);
      }
    }
  }
  accS[0] += *(const f32x4*)(bos + 32*w + 4*lq);
  accS[1] += *(const f32x4*)(bos + 32*w + 16 + 4*lq);

  // ---- epilogue A: out_s = LN(s + out_s) ----
  __syncthreads();                       // done reading emb2
  {
    float* scr = (float*)smem;           // [16][260] f32 (padded)
    *(f32x4*)(scr + l16*260 + 32*w + 4*lq)      = accS[0];
    *(f32x4*)(scr + l16*260 + 32*w + 16 + 4*lq) = accS[1];
  }
  __syncthreads();
  {
    int rr = tid >> 5, g = tid & 31, c0 = g*8;
    const float* srow = s + (size_t)(row0+rr)*256 + c0;
    f32x4 s0 = *(const f32x4*)srow, s1 = *(const f32x4*)(srow+4);
    const float* scr = (const float*)smem + rr*260 + c0;
    f32x4 o0 = *(const f32x4*)scr, o1 = *(const f32x4*)(scr+4);
    float xv[8]; float sum=0.f, sq=0.f;
#pragma unroll
    for (int k2=0;k2<4;++k2){ xv[k2]=s0[k2]+o0[k2]; xv[4+k2]=s1[k2]+o1[k2]; }
#pragma unroll
    for (int k2=0;k2<8;++k2){ sum += xv[k2]; sq += xv[k2]*xv[k2]; }
#pragma unroll
    for (int mk=1; mk<32; mk<<=1){ sum += __shfl_xor(sum, mk, 64); sq += __shfl_xor(sq, mk, 64); }
    float mu = sum*(1.0f/256.0f);
    float var = sq*(1.0f/256.0f) - mu*mu;
    float rs = rsqrtf(var + 1e-5f);
    f32x4 ga = *(const f32x4*)(gamma_s+c0), gb = *(const f32x4*)(gamma_s+c0+4);
    f32x4 ba = *(const f32x4*)(beta_s+c0),  bb = *(const f32x4*)(beta_s+c0+4);
    f32x4 r0, r1;
#pragma unroll
    for (int k2=0;k2<4;++k2){
      r0[k2] = (xv[k2]  -mu)*rs*ga[k2] + ba[k2];
      r1[k2] = (xv[4+k2]-mu)*rs*gb[k2] + bb[k2];
    }
    float* orow = out + (size_t)(row0+rr)*256 + c0;
    *(f32x4*)orow = r0; *(f32x4*)(orow+4) = r1;
  }
  // ---- epilogue B: equivariant vector norm ----
  __syncthreads();
  {
    float* scr = (float*)smem;           // [16][388] f32 (padded), [r][m*128+c]
#pragma unroll
    for (int m3=0;m3<3;++m3)
      *(f32x4*)(scr + l16*388 + m3*128 + 16*w + 4*lq) = accV[m3];
  }
  __syncthreads();
  {
    int rr = tid >> 5, g = tid & 31, c0 = g*4;
    const float* vrow = v + (size_t)(row0+rr)*384 + c0*3;
    f32x4 vv0 = *(const f32x4*)(vrow);
    f32x4 vv1 = *(const f32x4*)(vrow+4);
    f32x4 vv2 = *(const f32x4*)(vrow+8);
    const float* scr = (const float*)smem + rr*388;
    float vr[12]; float ss = 0.f;
#pragma unroll
    for (int f=0; f<12; ++f){
      int k = f/3, m3 = f%3;
      float base = (f<4) ? vv0[f] : ((f<8) ? vv1[f-4] : vv2[f-8]);
      float val = base + scr[m3*128 + c0 + k];
      vr[f] = val; ss += val*val;
    }
#pragma unroll
    for (int mk=1; mk<32; mk<<=1) ss += __shfl_xor(ss, mk, 64);
    float inv = rsqrtf(ss*(1.0f/128.0f) + 1e-5f);
    f32x4 gvv = *(const f32x4*)(gamma_v + c0);
    f32x4 o0, o1, o2;
#pragma unroll
    for (int f=0; f<12; ++f){
      float val = vr[f]*inv*gvv[f/3];
      if (f<4) o0[f]=val; else if (f<8) o1[f-4]=val; else o2[f-8]=val;
    }
    float* orow = out + (size_t)NROWS*256 + (size_t)(row0+rr)*384 + c0*3;
    *(f32x4*)(orow) = o0; *(f32x4*)(orow+4) = o1; *(f32x4*)(orow+8) = o2;
  }
}

extern "C" void kernel_launch(void* const* d_in, const int* in_sizes, int n_in,
                              void* d_out, int out_size, void* d_ws, size_t ws_size,
                              hipStream_t stream)
{
  const float* s   = (const float*)d_in[0];
  const float* v   = (const float*)d_in[1];
  const float* Ws  = (const float*)d_in[2];
  const float* bs  = (const float*)d_in[3];
  const float* Wv  = (const float*)d_in[4];
  const float* W2  = (const float*)d_in[5];
  const float* b2  = (const float*)d_in[6];
  const float* Wos = (const float*)d_in[7];
  const float* bos = (const float*)d_in[8];
  const float* Wov = (const float*)d_in[9];
  const float* gs  = (const float*)d_in[10];
  const float* bts = (const float*)d_in[11];
  const float* gv  = (const float*)d_in[12];
  float* out = (float*)d_out;
  unsigned short* wbf = (unsigned short*)d_ws;   // 655,360 B of bf16 weights

  prep_weights<<<640, 512, 0, stream>>>(Ws, Wv, W2, Wos, Wov, wbf);
  nt_fused<<<NROWS/BR, NT, 0, stream>>>(s, v, wbf, bs, b2, bos, gs, bts, gv, out);
}

// Round 3
// 211.855 us; speedup vs baseline: 1.9823x; 1.4255x over previous
//
#include <hip/hip_runtime.h>
#include <math.h>

#define NT 512
#define BR 16
#define NROWS 32768

typedef __attribute__((ext_vector_type(8))) short bf16x8;
typedef __attribute__((ext_vector_type(4))) float f32x4;
typedef __attribute__((ext_vector_type(2))) float f32x2;
typedef __attribute__((ext_vector_type(2))) unsigned int u32x2;

__device__ __forceinline__ unsigned pk2(float a, float b){
  unsigned ua = __float_as_uint(a); ua += 0x7FFFu + ((ua>>16)&1u);
  unsigned ub = __float_as_uint(b); ub += 0x7FFFu + ((ub>>16)&1u);
  return (ua>>16) | (ub & 0xFFFF0000u);
}
__device__ __forceinline__ unsigned short bf1(float a){
  unsigned ua = __float_as_uint(a); ua += 0x7FFFu + ((ua>>16)&1u);
  return (unsigned short)(ua>>16);
}

__device__ __forceinline__ float exp2_fast(float x){
#if __has_builtin(__builtin_amdgcn_exp2f)
  return __builtin_amdgcn_exp2f(x);
#else
  float r; asm("v_exp_f32 %0, %1" : "=v"(r) : "v"(x)); return r;
#endif
}
__device__ __forceinline__ float rcp_fast(float x){
#if __has_builtin(__builtin_amdgcn_rcpf)
  return __builtin_amdgcn_rcpf(x);
#else
  float r; asm("v_rcp_f32 %0, %1" : "=v"(r) : "v"(x)); return r;
#endif
}

__device__ __forceinline__ f32x2 v2(float x){ f32x2 r; r.x = x; r.y = x; return r; }
__device__ __forceinline__ f32x2 fma2(f32x2 a, f32x2 b, f32x2 c){
  return __builtin_elementwise_fma(a, b, c);
}

#define MFMA(a,b,c) __builtin_amdgcn_mfma_f32_16x16x32_bf16((a),(b),(c),0,0,0)

__global__ void prep_weights(const float* __restrict__ Ws, const float* __restrict__ Wv,
                             const float* __restrict__ W2, const float* __restrict__ Wos,
                             const float* __restrict__ Wov, unsigned short* __restrict__ o){
  int i = blockIdx.x*512 + threadIdx.x;
  if (i >= 327680) return;
  float val;
  if (i < 65536)       val = Ws[i];
  else if (i < 98304)  val = Wv[i-65536];
  else if (i < 229376) val = W2[i-98304];
  else if (i < 294912) val = Wos[i-229376];
  else                 val = Wov[i-294912];
  o[i] = bf1(val);
}

// ---- SeparableS2Activation (lmax=1, 4x5 grid), 2-wide packed, all scalings
// folded into constants.  xh = -log2(e)*(T·x); u = xh*rcp(1+exp2(xh));
// accum consts pre-multiplied by -ln2*F*w  (so sum == original quadrature).
__device__ __forceinline__ void s2act2(f32x2 x0, f32x2 x1, f32x2 x2, f32x2 x3,
                                       f32x2 yy[4]){
  { // l=0 scalar branch: silu(x0)
    f32x2 xn = v2(-1.44269504f) * x0;
    f32x2 e; e.x = exp2_fast(xn.x); e.y = exp2_fast(xn.y);
    f32x2 den = e + v2(1.0f);
    f32x2 r; r.x = rcp_fast(den.x); r.y = rcp_fast(den.y);
    yy[0] = x0 * r;
  }
  f32x2 t   = v2(-0.40697676f) * x0;
  f32x2 cb0 = fma2(v2( 0.60701885f), x2, t);
  f32x2 cb1 = fma2(v2( 0.23965414f), x2, t);
  f32x2 cb2 = fma2(v2(-0.23965414f), x2, t);
  f32x2 cb3 = fma2(v2(-0.60701885f), x2, t);
  f32x2 d1o = v2(-0.35835520f) * x1, d3o = v2(-0.35835520f) * x3;
  f32x2 d1i = v2(-0.66291491f) * x1, d3i = v2(-0.66291491f) * x3;
  f32x2 a1 = v2(0.f), a2 = v2(0.f), a3 = v2(0.f);
#define PT(xh_expr, S1, S2, S3) { \
    f32x2 xh = (xh_expr); \
    f32x2 e; e.x = exp2_fast(xh.x); e.y = exp2_fast(xh.y); \
    f32x2 den = e + v2(1.0f); \
    f32x2 r; r.x = rcp_fast(den.x); r.y = rcp_fast(den.y); \
    f32x2 u = xh * r; \
    a1 = fma2(v2(S1), u, a1); \
    a2 = fma2(v2(S2), u, a2); \
    a3 = fma2(v2(S3), u, a3); }
#define PT0(xh_expr, S2, S3) { \
    f32x2 xh = (xh_expr); \
    f32x2 e; e.x = exp2_fast(xh.x); e.y = exp2_fast(xh.y); \
    f32x2 den = e + v2(1.0f); \
    f32x2 r; r.x = rcp_fast(den.x); r.y = rcp_fast(den.y); \
    f32x2 u = xh * r; \
    a2 = fma2(v2(S2), u, a2); \
    a3 = fma2(v2(S3), u, a3); }
#define RING(cb, d1, d3, WZ, A1, A2, B0, B1, B2) \
  PT0(cb + d3, WZ, B0) \
  PT(fma2(v2( 0.30901699f), d3, fma2(v2( 0.95105652f), d1, cb)),  A1, WZ,  B1) \
  PT(fma2(v2(-0.80901699f), d3, fma2(v2( 0.58778525f), d1, cb)),  A2, WZ, -(B2)) \
  PT(fma2(v2(-0.80901699f), d3, fma2(v2(-0.58778525f), d1, cb)), -(A2), WZ, -(B2)) \
  PT(fma2(v2( 0.30901699f), d3, fma2(v2(-0.95105652f), d1, cb)), -(A1), WZ,  B1)
  RING(cb0, d1o, d3o,  0.12748554f, -0.07157788f, -0.04423758f, -0.07526144f, -0.02325707f, -0.06088778f)
  RING(cb1, d1i, d3i,  0.09436044f, -0.24823853f, -0.15341984f, -0.26101343f, -0.08065758f, -0.21116430f)
  RING(cb2, d1i, d3i, -0.09436044f, -0.24823853f, -0.15341984f, -0.26101343f, -0.08065758f, -0.21116430f)
  RING(cb3, d1o, d3o, -0.12748554f, -0.07157788f, -0.04423758f, -0.07526144f, -0.02325707f, -0.06088778f)
#undef RING
#undef PT
#undef PT0
  yy[1] = a1; yy[2] = a2; yy[3] = a3;
}

// sep_act on one wave's accumulators; writes bf16 emb tile to LDS (swizzled).
// acc[m][ht2] holds D[col=r=l16][row = 32w+16*ht2+4*lq+j], j=0..3.
__device__ __forceinline__ void sep_store(const f32x4 (&acc)[4][2],
                                          char* smem, int w, int l16, int lq){
#pragma unroll
  for (int ht2=0; ht2<2; ++ht2){
    f32x2 Y[4][2];
#pragma unroll
    for (int jp=0; jp<2; ++jp){
      f32x2 x0,x1,x2,x3;
      x0.x = acc[0][ht2][2*jp]; x0.y = acc[0][ht2][2*jp+1];
      x1.x = acc[1][ht2][2*jp]; x1.y = acc[1][ht2][2*jp+1];
      x2.x = acc[2][ht2][2*jp]; x2.y = acc[2][ht2][2*jp+1];
      x3.x = acc[3][ht2][2*jp]; x3.y = acc[3][ht2][2*jp+1];
      f32x2 yy[4];
      s2act2(x0,x1,x2,x3, yy);
#pragma unroll
      for (int m=0;m<4;++m) Y[m][jp] = yy[m];
    }
    int h0 = 32*w + 16*ht2 + 4*lq;
#pragma unroll
    for (int m=0;m<4;++m){
      u32x2 p; p.x = pk2(Y[m][0].x, Y[m][0].y); p.y = pk2(Y[m][1].x, Y[m][1].y);
      int off = (l16*2048 + m*512 + h0*2) ^ ((l16&7)<<4);
      *(u32x2*)(smem + off) = p;
    }
  }
}

__global__ void __launch_bounds__(NT, 4) nt_fused(
    const float* __restrict__ s, const float* __restrict__ v,
    const unsigned short* __restrict__ wbf,
    const float* __restrict__ bs, const float* __restrict__ b2,
    const float* __restrict__ bos,
    const float* __restrict__ gamma_s, const float* __restrict__ beta_s,
    const float* __restrict__ gamma_v,
    float* __restrict__ out)
{
  __shared__ __align__(128) char smem[32768];
  const int tid = threadIdx.x;
  const int w = tid >> 6;
  const int lane = tid & 63;
  const int l16 = lane & 15, lq = lane >> 4;
  const int row0 = blockIdx.x * BR;

  // ---- stage s tile -> bf16 LDS [16][256] (swizzled), base 0 ----
#pragma unroll
  for (int it=0; it<2; ++it){
    int i = tid + it*512;               // 0..1023  (16 rows x 64 float4)
    int r = i >> 6, c = (i & 63) * 4;
    f32x4 fv = *(const f32x4*)(s + (size_t)(row0+r)*256 + c);
    u32x2 p; p.x = pk2(fv[0], fv[1]); p.y = pk2(fv[2], fv[3]);
    int off = (r*512 + c*2) ^ ((r&7)<<4);
    *(u32x2*)(smem + off) = p;
  }
  // ---- stage v tile -> bf16 LDS [16][3][128] (transposed, swizzled), base 8192 ----
#pragma unroll
  for (int it=0; it<3; ++it){
    int i = tid + it*512;               // 0..1535  (16 rows x 96 float4)
    int r = i / 96, fb = (i % 96) * 4;
    f32x4 fv = *(const f32x4*)(v + (size_t)(row0+r)*384 + fb);
#pragma unroll
    for (int k2=0;k2<4;++k2){
      int flat = fb + k2;
      int c = flat/3, m3 = flat%3;      // v[r][c][m] -> vT[r][m][c]
      int off = 8192 + ((r*768 + m3*256 + c*2) ^ ((r&7)<<4));
      *(unsigned short*)(smem + off) = bf1(fv[k2]);
    }
  }
  __syncthreads();

  const unsigned short* Ws  = wbf;
  const unsigned short* Wv  = wbf + 65536;
  const unsigned short* W20 = wbf + 98304;
  const unsigned short* W21 = wbf + 163840;
  const unsigned short* Wos = wbf + 229376;
  const unsigned short* Wov = wbf + 294912;

  const f32x4 zero = {0.f,0.f,0.f,0.f};
  f32x4 acc[4][2];
#pragma unroll
  for (int m=0;m<4;++m){ acc[m][0]=zero; acc[m][1]=zero; }

  // ---- GEMM1: emb = [s@Ws^T ; vT@Wv^T]  (A=weights, B=activation rows) ----
  {
    const int h0 = 32*w + l16, h1 = h0 + 16;
#pragma unroll
    for (int ks=0;ks<8;++ks){
      int k = ks*32 + lq*8;
      bf16x8 a0 = *(const bf16x8*)(Ws + h0*256 + k);
      bf16x8 a1 = *(const bf16x8*)(Ws + h1*256 + k);
      bf16x8 b  = *(const bf16x8*)(smem + ((l16*512 + k*2) ^ ((l16&7)<<4)));
      acc[0][0] = MFMA(a0,b,acc[0][0]);
      acc[0][1] = MFMA(a1,b,acc[0][1]);
    }
#pragma unroll
    for (int ks=0;ks<4;++ks){
      int k = ks*32 + lq*8;
      bf16x8 a0 = *(const bf16x8*)(Wv + (32*w + l16)*128 + k);
      bf16x8 a1 = *(const bf16x8*)(Wv + (32*w + 16 + l16)*128 + k);
#pragma unroll
      for (int m3=0;m3<3;++m3){
        bf16x8 b = *(const bf16x8*)(smem + (8192 + ((l16*768 + m3*256 + k*2) ^ ((l16&7)<<4))));
        acc[1+m3][0] = MFMA(a0,b,acc[1+m3][0]);
        acc[1+m3][1] = MFMA(a1,b,acc[1+m3][1]);
      }
    }
  }
  acc[0][0] += *(const f32x4*)(bs + 32*w + 4*lq);
  acc[0][1] += *(const f32x4*)(bs + 32*w + 16 + 4*lq);

  __syncthreads();                       // all waves done reading s/v tiles
  sep_store(acc, smem, w, l16, lq);      // emb -> LDS [16][4][256]
  __syncthreads();

  // ---- GEMM2: per-m weights W2[0]/W2[1], K=256 ----
  f32x4 acc2[4][2];
#pragma unroll
  for (int m=0;m<4;++m){ acc2[m][0]=zero; acc2[m][1]=zero; }
  {
    const int h0 = 32*w + l16, h1 = h0 + 16;
#pragma unroll
    for (int ks=0;ks<8;++ks){
      int k = ks*32 + lq*8;
      bf16x8 a00 = *(const bf16x8*)(W20 + h0*256 + k);
      bf16x8 a01 = *(const bf16x8*)(W20 + h1*256 + k);
      bf16x8 a10 = *(const bf16x8*)(W21 + h0*256 + k);
      bf16x8 a11 = *(const bf16x8*)(W21 + h1*256 + k);
#pragma unroll
      for (int m=0;m<4;++m){
        bf16x8 b = *(const bf16x8*)(smem + ((l16*2048 + m*512 + k*2) ^ ((l16&7)<<4)));
        acc2[m][0] = MFMA((m==0)?a00:a10, b, acc2[m][0]);
        acc2[m][1] = MFMA((m==0)?a01:a11, b, acc2[m][1]);
      }
    }
  }
  acc2[0][0] += *(const f32x4*)(b2 + 32*w + 4*lq);
  acc2[0][1] += *(const f32x4*)(b2 + 32*w + 16 + 4*lq);

  __syncthreads();
  sep_store(acc2, smem, w, l16, lq);     // emb2 -> LDS (in place)
  __syncthreads();

  // ---- GEMM3: out_s (Wos, 256 out) + out_v (Wov, 128 out x 3m) ----
  f32x4 accS[2]; accS[0]=zero; accS[1]=zero;
  f32x4 accV[3]; accV[0]=zero; accV[1]=zero; accV[2]=zero;
  {
    const int hs0 = 32*w + l16, hs1 = hs0 + 16;
    const int hv  = 16*w + l16;
#pragma unroll
    for (int ks=0;ks<8;++ks){
      int k = ks*32 + lq*8;
      bf16x8 as0 = *(const bf16x8*)(Wos + hs0*256 + k);
      bf16x8 as1 = *(const bf16x8*)(Wos + hs1*256 + k);
      bf16x8 av  = *(const bf16x8*)(Wov + hv*256 + k);
      bf16x8 b0  = *(const bf16x8*)(smem + ((l16*2048 + 0*512 + k*2) ^ ((l16&7)<<4)));
      accS[0] = MFMA(as0,b0,accS[0]);
      accS[1] = MFMA(as1,b0,accS[1]);
#pragma unroll
      for (int m3=0;m3<3;++m3){
        bf16x8 bm = *(const bf16x8*)(smem + ((l16*2048 + (1+m3)*512 + k*2) ^ ((l16&7)<<4)));
        accV[m3] = MFMA(av, bm, accV[m3]);
      }
    }
  }
  accS[0] += *(const f32x4*)(bos + 32*w + 4*lq);
  accS[1] += *(const f32x4*)(bos + 32*w + 16 + 4*lq);

  // ---- epilogue A: out_s = LN(s + out_s) ----
  __syncthreads();                       // done reading emb2
  {
    float* scr = (float*)smem;           // [16][260] f32 (padded)
    *(f32x4*)(scr + l16*260 + 32*w + 4*lq)      = accS[0];
    *(f32x4*)(scr + l16*260 + 32*w + 16 + 4*lq) = accS[1];
  }
  __syncthreads();
  {
    int rr = tid >> 5, g = tid & 31, c0 = g*8;
    const float* srow = s + (size_t)(row0+rr)*256 + c0;
    f32x4 s0 = *(const f32x4*)srow, s1 = *(const f32x4*)(srow+4);
    const float* scr = (const float*)smem + rr*260 + c0;
    f32x4 o0 = *(const f32x4*)scr, o1 = *(const f32x4*)(scr+4);
    float xv[8]; float sum=0.f, sq=0.f;
#pragma unroll
    for (int k2=0;k2<4;++k2){ xv[k2]=s0[k2]+o0[k2]; xv[4+k2]=s1[k2]+o1[k2]; }
#pragma unroll
    for (int k2=0;k2<8;++k2){ sum += xv[k2]; sq += xv[k2]*xv[k2]; }
#pragma unroll
    for (int mk=1; mk<32; mk<<=1){ sum += __shfl_xor(sum, mk, 64); sq += __shfl_xor(sq, mk, 64); }
    float mu = sum*(1.0f/256.0f);
    float var = sq*(1.0f/256.0f) - mu*mu;
    float rs = rsqrtf(var + 1e-5f);
    f32x4 ga = *(const f32x4*)(gamma_s+c0), gb = *(const f32x4*)(gamma_s+c0+4);
    f32x4 ba = *(const f32x4*)(beta_s+c0),  bb = *(const f32x4*)(beta_s+c0+4);
    f32x4 r0, r1;
#pragma unroll
    for (int k2=0;k2<4;++k2){
      r0[k2] = (xv[k2]  -mu)*rs*ga[k2] + ba[k2];
      r1[k2] = (xv[4+k2]-mu)*rs*gb[k2] + bb[k2];
    }
    float* orow = out + (size_t)(row0+rr)*256 + c0;
    *(f32x4*)orow = r0; *(f32x4*)(orow+4) = r1;
  }
  // ---- epilogue B: equivariant vector norm ----
  __syncthreads();
  {
    float* scr = (float*)smem;           // [16][388] f32 (padded), [r][m*128+c]
#pragma unroll
    for (int m3=0;m3<3;++m3)
      *(f32x4*)(scr + l16*388 + m3*128 + 16*w + 4*lq) = accV[m3];
  }
  __syncthreads();
  {
    int rr = tid >> 5, g = tid & 31, c0 = g*4;
    const float* vrow = v + (size_t)(row0+rr)*384 + c0*3;
    f32x4 vv0 = *(const f32x4*)(vrow);
    f32x4 vv1 = *(const f32x4*)(vrow+4);
    f32x4 vv2 = *(const f32x4*)(vrow+8);
    const float* scr = (const float*)smem + rr*388;
    float vr[12]; float ss = 0.f;
#pragma unroll
    for (int f=0; f<12; ++f){
      int k = f/3, m3 = f%3;
      float base = (f<4) ? vv0[f] : ((f<8) ? vv1[f-4] : vv2[f-8]);
      float val = base + scr[m3*128 + c0 + k];
      vr[f] = val; ss += val*val;
    }
#pragma unroll
    for (int mk=1; mk<32; mk<<=1) ss += __shfl_xor(ss, mk, 64);
    float inv = rsqrtf(ss*(1.0f/128.0f) + 1e-5f);
    f32x4 gvv = *(const f32x4*)(gamma_v + c0);
    f32x4 o0, o1, o2;
#pragma unroll
    for (int f=0; f<12; ++f){
      float val = vr[f]*inv*gvv[f/3];
      if (f<4) o0[f]=val; else if (f<8) o1[f-4]=val; else o2[f-8]=val;
    }
    float* orow = out + (size_t)NROWS*256 + (size_t)(row0+rr)*384 + c0*3;
    *(f32x4*)(orow) = o0; *(f32x4*)(orow+4) = o1; *(f32x4*)(orow+8) = o2;
  }
}

extern "C" void kernel_launch(void* const* d_in, const int* in_sizes, int n_in,
                              void* d_out, int out_size, void* d_ws, size_t ws_size,
                              hipStream_t stream)
{
  const float* s   = (const float*)d_in[0];
  const float* v   = (const float*)d_in[1];
  const float* Ws  = (const float*)d_in[2];
  const float* bs  = (const float*)d_in[3];
  const float* Wv  = (const float*)d_in[4];
  const float* W2  = (const float*)d_in[5];
  const float* b2  = (const float*)d_in[6];
  const float* Wos = (const float*)d_in[7];
  const float* bos = (const float*)d_in[8];
  const float* Wov = (const float*)d_in[9];
  const float* gs  = (const float*)d_in[10];
  const float* bts = (const float*)d_in[11];
  const float* gv  = (const float*)d_in[12];
  float* out = (float*)d_out;
  unsigned short* wbf = (unsigned short*)d_ws;   // 655,360 B of bf16 weights

  prep_weights<<<640, 512, 0, stream>>>(Ws, Wv, W2, Wos, Wov, wbf);
  nt_fused<<<NROWS/BR, NT, 0, stream>>>(s, v, wbf, bs, b2, bos, gs, bts, gv, out);
}

// Round 5
// 182.501 us; speedup vs baseline: 2.3011x; 1.1608x over previous
//
#include <hip/hip_runtime.h>
#include <math.h>

#define NT 512
#define BR 32
#define NROWS 32768

typedef __attribute__((ext_vector_type(8))) short bf16x8;
typedef __attribute__((ext_vector_type(4))) float f32x4;
typedef __attribute__((ext_vector_type(2))) float f32x2;
typedef __attribute__((ext_vector_type(2))) unsigned int u32x2;

__device__ __forceinline__ unsigned pk2(float a, float b){
  unsigned ua = __float_as_uint(a); ua += 0x7FFFu + ((ua>>16)&1u);
  unsigned ub = __float_as_uint(b); ub += 0x7FFFu + ((ub>>16)&1u);
  return (ua>>16) | (ub & 0xFFFF0000u);
}
__device__ __forceinline__ unsigned short bf1(float a){
  unsigned ua = __float_as_uint(a); ua += 0x7FFFu + ((ua>>16)&1u);
  return (unsigned short)(ua>>16);
}

__device__ __forceinline__ float exp2_fast(float x){
#if __has_builtin(__builtin_amdgcn_exp2f)
  return __builtin_amdgcn_exp2f(x);
#else
  float r; asm("v_exp_f32 %0, %1" : "=v"(r) : "v"(x)); return r;
#endif
}
__device__ __forceinline__ float rcp_fast(float x){
#if __has_builtin(__builtin_amdgcn_rcpf)
  return __builtin_amdgcn_rcpf(x);
#else
  float r; asm("v_rcp_f32 %0, %1" : "=v"(r) : "v"(x)); return r;
#endif
}

__device__ __forceinline__ f32x2 v2(float x){ f32x2 r; r.x = x; r.y = x; return r; }
__device__ __forceinline__ f32x2 fma2(f32x2 a, f32x2 b, f32x2 c){
  return __builtin_elementwise_fma(a, b, c);
}

#define MFMA(a,b,c) __builtin_amdgcn_mfma_f32_16x16x32_bf16((a),(b),(c),0,0,0)

__global__ void prep_weights(const float* __restrict__ Ws, const float* __restrict__ Wv,
                             const float* __restrict__ W2, const float* __restrict__ Wos,
                             const float* __restrict__ Wov, unsigned short* __restrict__ o){
  int i = blockIdx.x*512 + threadIdx.x;
  if (i >= 327680) return;
  float val;
  if (i < 65536)       val = Ws[i];
  else if (i < 98304)  val = Wv[i-65536];
  else if (i < 229376) val = W2[i-98304];
  else if (i < 294912) val = Wos[i-229376];
  else                 val = Wov[i-294912];
  o[i] = bf1(val);
}

// ---- SeparableS2Activation (lmax=1, 4x5 grid), 2-wide packed, all scalings
// folded into constants.  xh = -log2(e)*(T·x); u = xh*rcp(1+exp2(xh));
// accum consts pre-multiplied by -ln2*F*w  (so sum == original quadrature).
__device__ __forceinline__ void s2act2(f32x2 x0, f32x2 x1, f32x2 x2, f32x2 x3,
                                       f32x2 yy[4]){
  { // l=0 scalar branch: silu(x0)
    f32x2 xn = v2(-1.44269504f) * x0;
    f32x2 e; e.x = exp2_fast(xn.x); e.y = exp2_fast(xn.y);
    f32x2 den = e + v2(1.0f);
    f32x2 r; r.x = rcp_fast(den.x); r.y = rcp_fast(den.y);
    yy[0] = x0 * r;
  }
  f32x2 t   = v2(-0.40697676f) * x0;
  f32x2 cb0 = fma2(v2( 0.60701885f), x2, t);
  f32x2 cb1 = fma2(v2( 0.23965414f), x2, t);
  f32x2 cb2 = fma2(v2(-0.23965414f), x2, t);
  f32x2 cb3 = fma2(v2(-0.60701885f), x2, t);
  f32x2 d1o = v2(-0.35835520f) * x1, d3o = v2(-0.35835520f) * x3;
  f32x2 d1i = v2(-0.66291491f) * x1, d3i = v2(-0.66291491f) * x3;
  f32x2 a1 = v2(0.f), a2 = v2(0.f), a3 = v2(0.f);
#define PT(xh_expr, S1, S2, S3) { \
    f32x2 xh = (xh_expr); \
    f32x2 e; e.x = exp2_fast(xh.x); e.y = exp2_fast(xh.y); \
    f32x2 den = e + v2(1.0f); \
    f32x2 r; r.x = rcp_fast(den.x); r.y = rcp_fast(den.y); \
    f32x2 u = xh * r; \
    a1 = fma2(v2(S1), u, a1); \
    a2 = fma2(v2(S2), u, a2); \
    a3 = fma2(v2(S3), u, a3); }
#define PT0(xh_expr, S2, S3) { \
    f32x2 xh = (xh_expr); \
    f32x2 e; e.x = exp2_fast(xh.x); e.y = exp2_fast(xh.y); \
    f32x2 den = e + v2(1.0f); \
    f32x2 r; r.x = rcp_fast(den.x); r.y = rcp_fast(den.y); \
    f32x2 u = xh * r; \
    a2 = fma2(v2(S2), u, a2); \
    a3 = fma2(v2(S3), u, a3); }
#define RING(cb, d1, d3, WZ, A1, A2, B0, B1, B2) \
  PT0(cb + d3, WZ, B0) \
  PT(fma2(v2( 0.30901699f), d3, fma2(v2( 0.95105652f), d1, cb)),  A1, WZ,  B1) \
  PT(fma2(v2(-0.80901699f), d3, fma2(v2( 0.58778525f), d1, cb)),  A2, WZ, -(B2)) \
  PT(fma2(v2(-0.80901699f), d3, fma2(v2(-0.58778525f), d1, cb)), -(A2), WZ, -(B2)) \
  PT(fma2(v2( 0.30901699f), d3, fma2(v2(-0.95105652f), d1, cb)), -(A1), WZ,  B1)
  RING(cb0, d1o, d3o,  0.12748554f, -0.07157788f, -0.04423758f, -0.07526144f, -0.02325707f, -0.06088778f)
  RING(cb1, d1i, d3i,  0.09436044f, -0.24823853f, -0.15341984f, -0.26101343f, -0.08065758f, -0.21116430f)
  RING(cb2, d1i, d3i, -0.09436044f, -0.24823853f, -0.15341984f, -0.26101343f, -0.08065758f, -0.21116430f)
  RING(cb3, d1o, d3o, -0.12748554f, -0.07157788f, -0.04423758f, -0.07526144f, -0.02325707f, -0.06088778f)
#undef RING
#undef PT
#undef PT0
  yy[1] = a1; yy[2] = a2; yy[3] = a3;
}

// sep_act on one wave's accumulators (2 b-tiles); writes bf16 emb tile to LDS.
// acc[m][hj][bt]: D col = row r = bt*16+l16; D row = ch 32w+hj*16+4lq+j.
__device__ __forceinline__ void sep_store(const f32x4 (&acc)[4][2][2],
                                          char* smem, int w, int l16, int lq){
  const int sw = (l16 & 7) << 4;
#pragma unroll
  for (int bt=0; bt<2; ++bt){
#pragma unroll
    for (int hj=0; hj<2; ++hj){
      f32x2 Y[4][2];
#pragma unroll
      for (int jp=0; jp<2; ++jp){
        f32x2 x0,x1,x2,x3;
        x0.x = acc[0][hj][bt][2*jp]; x0.y = acc[0][hj][bt][2*jp+1];
        x1.x = acc[1][hj][bt][2*jp]; x1.y = acc[1][hj][bt][2*jp+1];
        x2.x = acc[2][hj][bt][2*jp]; x2.y = acc[2][hj][bt][2*jp+1];
        x3.x = acc[3][hj][bt][2*jp]; x3.y = acc[3][hj][bt][2*jp+1];
        f32x2 yy[4];
        s2act2(x0,x1,x2,x3, yy);
#pragma unroll
        for (int m=0;m<4;++m) Y[m][jp] = yy[m];
      }
      int r  = bt*16 + l16;
      int h0 = 32*w + hj*16 + 4*lq;
#pragma unroll
      for (int m=0;m<4;++m){
        u32x2 p; p.x = pk2(Y[m][0].x, Y[m][0].y); p.y = pk2(Y[m][1].x, Y[m][1].y);
        int off = (r*2048 + m*512 + h0*2) ^ sw;
        *(u32x2*)(smem + off) = p;
      }
    }
  }
}

__global__ void __launch_bounds__(NT, 4) nt_fused(
    const float* __restrict__ s, const float* __restrict__ v,
    const unsigned short* __restrict__ wbf,
    const float* __restrict__ bs, const float* __restrict__ b2,
    const float* __restrict__ bos,
    const float* __restrict__ gamma_s, const float* __restrict__ beta_s,
    const float* __restrict__ gamma_v,
    float* __restrict__ out)
{
  __shared__ __align__(128) char smem[65536];
  const int tid = threadIdx.x;
  const int w = tid >> 6;
  const int lane = tid & 63;
  const int l16 = lane & 15, lq = lane >> 4;
  const int sw = (l16 & 7) << 4;
  const int row0 = blockIdx.x * BR;

  // ---- stage s tile -> bf16 LDS [32][256] (swizzled), base 0 ----
#pragma unroll
  for (int it=0; it<4; ++it){
    int i = tid + it*512;               // 0..2047  (32 rows x 64 float4)
    int r = i >> 6, c = (i & 63) * 4;
    f32x4 fv = *(const f32x4*)(s + (size_t)(row0+r)*256 + c);
    u32x2 p; p.x = pk2(fv[0], fv[1]); p.y = pk2(fv[2], fv[3]);
    int off = (r*512 + c*2) ^ ((r&7)<<4);
    *(u32x2*)(smem + off) = p;
  }
  // ---- stage v tile -> bf16 LDS [32][3][128] (transposed, swizzled), base 16384
  //      (R3-verbatim element-wise form, extended to 32 rows) ----
#pragma unroll
  for (int it=0; it<6; ++it){
    int i = tid + it*512;               // 0..3071  (32 rows x 96 float4)
    int r = i / 96, fb = (i % 96) * 4;
    f32x4 fv = *(const f32x4*)(v + (size_t)(row0+r)*384 + fb);
#pragma unroll
    for (int k2=0;k2<4;++k2){
      int flat = fb + k2;
      int c = flat/3, m3 = flat%3;      // v[r][c][m] -> vT[r][m][c]
      int off = 16384 + ((r*768 + m3*256 + c*2) ^ ((r&7)<<4));
      *(unsigned short*)(smem + off) = bf1(fv[k2]);
    }
  }
  __syncthreads();

  const unsigned short* Ws  = wbf;
  const unsigned short* Wv  = wbf + 65536;
  const unsigned short* W20 = wbf + 98304;
  const unsigned short* W21 = wbf + 163840;
  const unsigned short* Wos = wbf + 229376;
  const unsigned short* Wov = wbf + 294912;

  const int hA = 32*w + l16;
  const f32x4 zero = {0.f,0.f,0.f,0.f};
  f32x4 acc[4][2][2];
#pragma unroll
  for (int m=0;m<4;++m)
#pragma unroll
    for (int hj=0;hj<2;++hj){ acc[m][hj][0]=zero; acc[m][hj][1]=zero; }

  // ---- GEMM1: emb = [s@Ws^T ; vT@Wv^T]  (A=weights shared across 2 b-tiles) ----
  {
#pragma unroll
    for (int ks=0;ks<8;++ks){
      int k = ks*32 + lq*8;
      bf16x8 a0 = *(const bf16x8*)(Ws + hA*256 + k);
      bf16x8 a1 = *(const bf16x8*)(Ws + (hA+16)*256 + k);
#pragma unroll
      for (int bt=0;bt<2;++bt){
        bf16x8 b = *(const bf16x8*)(smem + (((bt*16+l16)*512 + k*2) ^ sw));
        acc[0][0][bt] = MFMA(a0,b,acc[0][0][bt]);
        acc[0][1][bt] = MFMA(a1,b,acc[0][1][bt]);
      }
    }
#pragma unroll
    for (int ks=0;ks<4;++ks){
      int k = ks*32 + lq*8;
      bf16x8 a0 = *(const bf16x8*)(Wv + hA*128 + k);
      bf16x8 a1 = *(const bf16x8*)(Wv + (hA+16)*128 + k);
#pragma unroll
      for (int m3=0;m3<3;++m3)
#pragma unroll
        for (int bt=0;bt<2;++bt){
          bf16x8 b = *(const bf16x8*)(smem + (16384 + (((bt*16+l16)*768 + m3*256 + k*2) ^ sw)));
          acc[1+m3][0][bt] = MFMA(a0,b,acc[1+m3][0][bt]);
          acc[1+m3][1][bt] = MFMA(a1,b,acc[1+m3][1][bt]);
        }
    }
  }
  {
    f32x4 bs0 = *(const f32x4*)(bs + 32*w + 4*lq);
    f32x4 bs1 = *(const f32x4*)(bs + 32*w + 16 + 4*lq);
#pragma unroll
    for (int bt=0;bt<2;++bt){ acc[0][0][bt] += bs0; acc[0][1][bt] += bs1; }
  }

  __syncthreads();                       // all waves done reading s/v tiles
  sep_store(acc, smem, w, l16, lq);      // emb -> LDS [32][4][256] bf16
  __syncthreads();

  // ---- GEMM2: per-m weights W2[0]/W2[1], K=256 ----
  f32x4 acc2[4][2][2];
#pragma unroll
  for (int m=0;m<4;++m)
#pragma unroll
    for (int hj=0;hj<2;++hj){ acc2[m][hj][0]=zero; acc2[m][hj][1]=zero; }
  {
#pragma unroll
    for (int ks=0;ks<8;++ks){
      int k = ks*32 + lq*8;
      bf16x8 a00 = *(const bf16x8*)(W20 + hA*256 + k);
      bf16x8 a01 = *(const bf16x8*)(W20 + (hA+16)*256 + k);
      bf16x8 a10 = *(const bf16x8*)(W21 + hA*256 + k);
      bf16x8 a11 = *(const bf16x8*)(W21 + (hA+16)*256 + k);
#pragma unroll
      for (int m=0;m<4;++m)
#pragma unroll
        for (int bt=0;bt<2;++bt){
          bf16x8 b = *(const bf16x8*)(smem + (((bt*16+l16)*2048 + m*512 + k*2) ^ sw));
          acc2[m][0][bt] = MFMA((m==0)?a00:a10, b, acc2[m][0][bt]);
          acc2[m][1][bt] = MFMA((m==0)?a01:a11, b, acc2[m][1][bt]);
        }
    }
  }
  {
    f32x4 b20 = *(const f32x4*)(b2 + 32*w + 4*lq);
    f32x4 b21 = *(const f32x4*)(b2 + 32*w + 16 + 4*lq);
#pragma unroll
    for (int bt=0;bt<2;++bt){ acc2[0][0][bt] += b20; acc2[0][1][bt] += b21; }
  }

  __syncthreads();
  sep_store(acc2, smem, w, l16, lq);     // emb2 -> LDS (in place)
  __syncthreads();

  // ---- GEMM3: out_s (Wos, 256 out) + out_v (Wov, 128 out x 3m) ----
  f32x4 accS[2][2]; f32x4 accV[3][2];
#pragma unroll
  for (int bt=0;bt<2;++bt){
    accS[0][bt]=zero; accS[1][bt]=zero;
    accV[0][bt]=zero; accV[1][bt]=zero; accV[2][bt]=zero;
  }
  {
    const int hv = 16*w + l16;
#pragma unroll
    for (int ks=0;ks<8;++ks){
      int k = ks*32 + lq*8;
      bf16x8 as0 = *(const bf16x8*)(Wos + hA*256 + k);
      bf16x8 as1 = *(const bf16x8*)(Wos + (hA+16)*256 + k);
      bf16x8 av  = *(const bf16x8*)(Wov + hv*256 + k);
#pragma unroll
      for (int bt=0;bt<2;++bt){
        int rb = (bt*16+l16)*2048;
        bf16x8 b0 = *(const bf16x8*)(smem + ((rb + k*2) ^ sw));
        accS[0][bt] = MFMA(as0,b0,accS[0][bt]);
        accS[1][bt] = MFMA(as1,b0,accS[1][bt]);
#pragma unroll
        for (int m3=0;m3<3;++m3){
          bf16x8 bm = *(const bf16x8*)(smem + ((rb + (1+m3)*512 + k*2) ^ sw));
          accV[m3][bt] = MFMA(av, bm, accV[m3][bt]);
        }
      }
    }
  }
  {
    f32x4 bo0 = *(const f32x4*)(bos + 32*w + 4*lq);
    f32x4 bo1 = *(const f32x4*)(bos + 32*w + 16 + 4*lq);
#pragma unroll
    for (int bt=0;bt<2;++bt){ accS[0][bt] += bo0; accS[1][bt] += bo1; }
  }

  // ---- epilogue A: out_s = LN(s + out_s)  (R3-verbatim body, two halves) ----
  __syncthreads();                       // done reading emb2
  {
    float* scr = (float*)smem;           // [32][260] f32 (padded)
#pragma unroll
    for (int bt=0;bt<2;++bt){
      int r = bt*16 + l16;
      *(f32x4*)(scr + r*260 + 32*w + 4*lq)      = accS[0][bt];
      *(f32x4*)(scr + r*260 + 32*w + 16 + 4*lq) = accS[1][bt];
    }
  }
  __syncthreads();
#pragma unroll
  for (int h=0; h<2; ++h){
    int rr = h*16 + (tid >> 5), g = tid & 31, c0 = g*8;
    const float* srow = s + (size_t)(row0+rr)*256 + c0;
    f32x4 s0 = *(const f32x4*)srow, s1 = *(const f32x4*)(srow+4);
    const float* scr = (const float*)smem + rr*260 + c0;
    f32x4 o0 = *(const f32x4*)scr, o1 = *(const f32x4*)(scr+4);
    float xv[8]; float sum=0.f, sq=0.f;
#pragma unroll
    for (int k2=0;k2<4;++k2){ xv[k2]=s0[k2]+o0[k2]; xv[4+k2]=s1[k2]+o1[k2]; }
#pragma unroll
    for (int k2=0;k2<8;++k2){ sum += xv[k2]; sq += xv[k2]*xv[k2]; }
#pragma unroll
    for (int mk=1; mk<32; mk<<=1){ sum += __shfl_xor(sum, mk, 64); sq += __shfl_xor(sq, mk, 64); }
    float mu = sum*(1.0f/256.0f);
    float var = sq*(1.0f/256.0f) - mu*mu;
    float rs = rsqrtf(var + 1e-5f);
    f32x4 ga = *(const f32x4*)(gamma_s+c0), gb = *(const f32x4*)(gamma_s+c0+4);
    f32x4 ba = *(const f32x4*)(beta_s+c0),  bb = *(const f32x4*)(beta_s+c0+4);
    f32x4 r0, r1;
#pragma unroll
    for (int k2=0;k2<4;++k2){
      r0[k2] = (xv[k2]  -mu)*rs*ga[k2] + ba[k2];
      r1[k2] = (xv[4+k2]-mu)*rs*gb[k2] + bb[k2];
    }
    float* orow = out + (size_t)(row0+rr)*256 + c0;
    *(f32x4*)orow = r0; *(f32x4*)(orow+4) = r1;
  }
  // ---- epilogue B: equivariant vector norm (R3-verbatim body, two halves) ----
  __syncthreads();
  {
    float* scr = (float*)smem;           // [32][388] f32 (padded), [r][m*128+c]
#pragma unroll
    for (int bt=0;bt<2;++bt){
      int r = bt*16 + l16;
#pragma unroll
      for (int m3=0;m3<3;++m3)
        *(f32x4*)(scr + r*388 + m3*128 + 16*w + 4*lq) = accV[m3][bt];
    }
  }
  __syncthreads();
#pragma unroll
  for (int h=0; h<2; ++h){
    int rr = h*16 + (tid >> 5), g = tid & 31, c0 = g*4;
    const float* vrow = v + (size_t)(row0+rr)*384 + c0*3;
    f32x4 vv0 = *(const f32x4*)(vrow);
    f32x4 vv1 = *(const f32x4*)(vrow+4);
    f32x4 vv2 = *(const f32x4*)(vrow+8);
    const float* scr = (const float*)smem + rr*388;
    float vr[12]; float ss = 0.f;
#pragma unroll
    for (int f=0; f<12; ++f){
      int k = f/3, m3 = f%3;
      float base = (f<4) ? vv0[f] : ((f<8) ? vv1[f-4] : vv2[f-8]);
      float val = base + scr[m3*128 + c0 + k];
      vr[f] = val; ss += val*val;
    }
#pragma unroll
    for (int mk=1; mk<32; mk<<=1) ss += __shfl_xor(ss, mk, 64);
    float inv = rsqrtf(ss*(1.0f/128.0f) + 1e-5f);
    f32x4 gvv = *(const f32x4*)(gamma_v + c0);
    f32x4 o0, o1, o2;
#pragma unroll
    for (int f=0; f<12; ++f){
      float val = vr[f]*inv*gvv[f/3];
      if (f<4) o0[f]=val; else if (f<8) o1[f-4]=val; else o2[f-8]=val;
    }
    float* orow = out + (size_t)NROWS*256 + (size_t)(row0+rr)*384 + c0*3;
    *(f32x4*)(orow) = o0; *(f32x4*)(orow+4) = o1; *(f32x4*)(orow+8) = o2;
  }
}

extern "C" void kernel_launch(void* const* d_in, const int* in_sizes, int n_in,
                              void* d_out, int out_size, void* d_ws, size_t ws_size,
                              hipStream_t stream)
{
  const float* s   = (const float*)d_in[0];
  const float* v   = (const float*)d_in[1];
  const float* Ws  = (const float*)d_in[2];
  const float* bs  = (const float*)d_in[3];
  const float* Wv  = (const float*)d_in[4];
  const float* W2  = (const float*)d_in[5];
  const float* b2  = (const float*)d_in[6];
  const float* Wos = (const float*)d_in[7];
  const float* bos = (const float*)d_in[8];
  const float* Wov = (const float*)d_in[9];
  const float* gs  = (const float*)d_in[10];
  const float* bts = (const float*)d_in[11];
  const float* gv  = (const float*)d_in[12];
  float* out = (float*)d_out;
  unsigned short* wbf = (unsigned short*)d_ws;   // 655,360 B of bf16 weights

  prep_weights<<<640, 512, 0, stream>>>(Ws, Wv, W2, Wos, Wov, wbf);
  nt_fused<<<NROWS/BR, NT, 0, stream>>>(s, v, wbf, bs, b2, bos, gs, bts, gv, out);
}